// Round 1
// baseline (620.495 us; speedup 1.0000x reference)
//
#include <hip/hip_runtime.h>
#include <math.h>

// One block per image. Fully fused:
//   phase 0: stage x (784) + U (256) into LDS
//   phase 1: conv3x3+avgpool -> dpool; 32 ds channels = pw_w[c]*dpool+pw_b[c] into padded tile
//   phase 2: quantum patches -> 4 channels into padded tile (scrambled channel layout per reference reshape)
//   phase 3: fused 3x3 conv 36->128 + bias + relu + shfl-pool -> flat[6272] in LDS
//   phase 4: classifier GEMV (11 outputs) with block reduction
//
// LDS carve (62 KB, fits 64 KB static limit; 2 blocks/CU):
//   [0, 9216)           tile: 36 ch x 16x16 (zero halo)
//   [9216, 9216+6272)   flat (phase 3+)  / aliased: xs(784)+u_s(256) (phases 0-2)
//   [15488, 15488+64)   reduction scratch

#define TILE_F (36 * 256)

__global__ __launch_bounds__(256) void quanv_fused(
    const float* __restrict__ x,      // (B,1,28,28)
    const float* __restrict__ dw_w,   // 9
    const float* __restrict__ pw_w,   // 32
    const float* __restrict__ pw_b,   // 32
    const float* __restrict__ U,      // 16x16
    const float* __restrict__ fus_w,  // 128*36*9
    const float* __restrict__ fus_b,  // 128
    const float* __restrict__ cls_w,  // 10*6272
    const float* __restrict__ cls_b,  // 10
    const float* __restrict__ reg_w,  // 6272
    const float* __restrict__ reg_b,  // 1
    float* __restrict__ out,          // B*10 logits, then B aux
    int B)
{
    __shared__ float smem[TILE_F + 6272 + 64];
    float* tile = smem;                    // 36*256
    float* flat = smem + TILE_F;           // 6272 (phase 3+)
    float* red  = smem + TILE_F + 6272;    // 44
    float* xs   = smem + TILE_F;           // alias (phases 0-2)
    float* u_s  = xs + 784;                // alias (phases 0-2)

    const int b   = blockIdx.x;
    const int tid = threadIdx.x;
    const float* xb = x + b * 784;

    // ---- phase 0: zero tile, stage image + U ----
    for (int i = tid; i < TILE_F; i += 256) tile[i] = 0.f;
    for (int i = tid; i < 784; i += 256) xs[i] = xb[i];
    u_s[tid] = U[tid];
    __syncthreads();

    // ---- phases 1+2: per-patch work (196 patches) ----
    if (tid < 196) {
        const int i = tid / 14, j = tid % 14;
        const int Y = 2 * i, X = 2 * j;

        // conv3x3 (pad 1) at the 4 patch pixels, then mean
        float w9[9];
        #pragma unroll
        for (int t = 0; t < 9; ++t) w9[t] = dw_w[t];
        float dsum = 0.f;
        #pragma unroll
        for (int dy = 0; dy < 2; ++dy) {
            #pragma unroll
            for (int dx = 0; dx < 2; ++dx) {
                const int cy = Y + dy, cx = X + dx;
                #pragma unroll
                for (int ky = 0; ky < 3; ++ky) {
                    const int yy = cy + ky - 1;
                    if (yy < 0 || yy > 27) continue;
                    #pragma unroll
                    for (int kx = 0; kx < 3; ++kx) {
                        const int xx = cx + kx - 1;
                        if (xx < 0 || xx > 27) continue;
                        dsum += xs[yy * 28 + xx] * w9[ky * 3 + kx];
                    }
                }
            }
        }
        const float dpool = 0.25f * dsum;
        const int sp_off = (i + 1) * 16 + (j + 1);
        #pragma unroll 8
        for (int c = 0; c < 32; ++c)
            tile[c * 256 + sp_off] = pw_w[c] * dpool + pw_b[c];

        // quantum patch: RY product state -> U -> PauliZ expectations
        const float p0 = xs[Y * 28 + X],       p1 = xs[Y * 28 + X + 1];
        const float p2 = xs[(Y + 1) * 28 + X], p3 = xs[(Y + 1) * 28 + X + 1];
        float c0, s0, c1, s1, c2, s2, c3, s3;
        sincosf(0.5f * p0, &s0, &c0);
        sincosf(0.5f * p1, &s1, &c1);
        sincosf(0.5f * p2, &s2, &c2);
        sincosf(0.5f * p3, &s3, &c3);
        float a01[4] = {c0 * c1, c0 * s1, s0 * c1, s0 * s1};
        float a23[4] = {c2 * c3, c2 * s3, s2 * c3, s2 * s3};
        float amp[16];
        #pragma unroll
        for (int hi = 0; hi < 4; ++hi)
            #pragma unroll
            for (int lo = 0; lo < 4; ++lo)
                amp[hi * 4 + lo] = a01[hi] * a23[lo];

        float meas[4] = {0.f, 0.f, 0.f, 0.f};
        #pragma unroll
        for (int m = 0; m < 16; ++m) {
            float st = 0.f;
            #pragma unroll
            for (int n = 0; n < 16; ++n) st = fmaf(u_s[m * 16 + n], amp[n], st);
            const float pm = st * st;
            meas[0] += ((m >> 3) & 1) ? -pm : pm;
            meas[1] += ((m >> 2) & 1) ? -pm : pm;
            meas[2] += ((m >> 1) & 1) ? -pm : pm;
            meas[3] += (m & 1) ? -pm : pm;
        }
        // reference does meas.reshape(B,784).reshape(B,4,14,14): flat f = i*56+j*4+w
        const int fbase = i * 56 + j * 4;
        #pragma unroll
        for (int w = 0; w < 4; ++w) {
            const int f  = fbase + w;
            const int ch = f / 196;
            const int sp = f - ch * 196;
            tile[(32 + ch) * 256 + (sp / 14 + 1) * 16 + (sp % 14) + 1] = meas[w];
        }
    }
    __syncthreads();

    // ---- phase 3: fused conv 36->128 + relu + pool ----
    const int y    = tid >> 4, xcol = tid & 15;
    const int ysC  = (y < 14) ? y : 13;       // clamp idle lanes in-bounds
    const int xsC  = (xcol < 14) ? xcol : 13;
    const bool sel = (y < 14) && (xcol < 14) && ((y & 1) == 0) && ((xcol & 1) == 0);
    const int fidx = (y >> 1) * 7 + (xcol >> 1);
    const float* tbase = tile + ysC * 16 + xsC;

    for (int ocb = 0; ocb < 16; ++ocb) {
        const int oc0 = ocb * 8;
        float acc[8];
        #pragma unroll
        for (int r = 0; r < 8; ++r) acc[r] = fus_b[oc0 + r];
        const float* wb = fus_w + oc0 * 324;

        for (int ic = 0; ic < 36; ++ic) {
            float win[9];
            const float* tc = tbase + ic * 256;
            #pragma unroll
            for (int ky = 0; ky < 3; ++ky)
                #pragma unroll
                for (int kx = 0; kx < 3; ++kx)
                    win[ky * 3 + kx] = tc[ky * 16 + kx];
            #pragma unroll
            for (int r = 0; r < 8; ++r) {
                const float* w = wb + r * 324 + ic * 9;   // uniform -> s_load
                #pragma unroll
                for (int t = 0; t < 9; ++t)
                    acc[r] = fmaf(w[t], win[t], acc[r]);
            }
        }
        #pragma unroll
        for (int r = 0; r < 8; ++r) {
            float v = acc[r] > 0.f ? acc[r] : 0.f;   // relu BEFORE pool
            v += __shfl_xor(v, 1, 64);               // pair columns 2j,2j+1
            v += __shfl_xor(v, 16, 64);              // pair rows 2i,2i+1
            if (sel) flat[(oc0 + r) * 49 + fidx] = 0.25f * v;
        }
    }
    __syncthreads();

    // ---- phase 4: classifier (10 logits + 1 aux) ----
    float acc11[11];
    #pragma unroll
    for (int k = 0; k < 11; ++k) acc11[k] = 0.f;
    for (int f = tid; f < 6272; f += 256) {
        const float v = flat[f];
        #pragma unroll
        for (int k = 0; k < 10; ++k)
            acc11[k] = fmaf(v, cls_w[k * 6272 + f], acc11[k]);
        acc11[10] = fmaf(v, reg_w[f], acc11[10]);
    }
    const int lane = tid & 63, wv = tid >> 6;
    #pragma unroll
    for (int k = 0; k < 11; ++k) {
        float a = acc11[k];
        #pragma unroll
        for (int off = 32; off > 0; off >>= 1) a += __shfl_down(a, off, 64);
        if (lane == 0) red[k * 4 + wv] = a;
    }
    __syncthreads();
    if (tid < 11) {
        const float v = red[tid * 4] + red[tid * 4 + 1] + red[tid * 4 + 2] + red[tid * 4 + 3];
        if (tid < 10) out[b * 10 + tid] = v + cls_b[tid];
        else          out[B * 10 + b]   = v + reg_b[0];
    }
}

extern "C" void kernel_launch(void* const* d_in, const int* in_sizes, int n_in,
                              void* d_out, int out_size, void* d_ws, size_t ws_size,
                              hipStream_t stream) {
    const float* x    = (const float*)d_in[0];
    const float* dw_w = (const float*)d_in[1];
    const float* pw_w = (const float*)d_in[2];
    const float* pw_b = (const float*)d_in[3];
    const float* U    = (const float*)d_in[4];
    const float* fw   = (const float*)d_in[5];
    const float* fb   = (const float*)d_in[6];
    const float* cw   = (const float*)d_in[7];
    const float* cb   = (const float*)d_in[8];
    const float* rw   = (const float*)d_in[9];
    const float* rb   = (const float*)d_in[10];
    const int B = in_sizes[0] / 784;

    quanv_fused<<<B, 256, 0, stream>>>(x, dw_w, pw_w, pw_b, U, fw, fb,
                                       cw, cb, rw, rb, (float*)d_out, B);
}

// Round 2
// 487.046 us; speedup vs baseline: 1.2740x; 1.2740x over previous
//
#include <hip/hip_runtime.h>
#include <math.h>

// One block per image, 256 threads. Fully fused, LDS-lean version:
//   phase 0: stage x (784) into LDS (U stays in global: wave-uniform -> s_load)
//   phase 1: conv3x3+avgpool -> dpool; 32 ds channels into padded tile
//   phase 2: quantum patches -> 4 channels into padded tile
//   phase 3: fused 3x3 conv 36->128 + bias + relu + shfl-pool; classifier GEMV
//            folded into the pooling epilogue (acc11 in registers)
//   phase 4: block-reduce 11 scalars -> out
//
// LDS carve (40,000 B -> 4 blocks/CU = 16 waves/CU = 50% occupancy):
//   [0, 9216)        tile: 36 ch x 16x16 (zero halo)
//   [9216, 10000)    xs: image (phases 0-2) / aliased: red[44] (phase 4)

#define TILE_F (36 * 256)

__global__ __launch_bounds__(256, 4) void quanv_fused(
    const float* __restrict__ x,      // (B,1,28,28)
    const float* __restrict__ dw_w,   // 9
    const float* __restrict__ pw_w,   // 32
    const float* __restrict__ pw_b,   // 32
    const float* __restrict__ U,      // 16x16
    const float* __restrict__ fus_w,  // 128*36*9
    const float* __restrict__ fus_b,  // 128
    const float* __restrict__ cls_w,  // 10*6272
    const float* __restrict__ cls_b,  // 10
    const float* __restrict__ reg_w,  // 6272
    const float* __restrict__ reg_b,  // 1
    float* __restrict__ out,          // B*10 logits, then B aux
    int B)
{
    __shared__ float smem[TILE_F + 784];
    float* tile = smem;                 // 36*256
    float* xs   = smem + TILE_F;        // 784 (phases 0-2)
    float* red  = smem + TILE_F;        // alias: 44 floats (phase 4)

    const int b   = blockIdx.x;
    const int tid = threadIdx.x;
    const float* xb = x + b * 784;

    // ---- phase 0: zero tile, stage image ----
    for (int i = tid; i < TILE_F; i += 256) tile[i] = 0.f;
    for (int i = tid; i < 784; i += 256) xs[i] = xb[i];
    __syncthreads();

    // ---- phases 1+2: per-patch work (196 patches) ----
    if (tid < 196) {
        const int i = tid / 14, j = tid % 14;
        const int Y = 2 * i, X = 2 * j;

        // conv3x3 (pad 1) at the 4 patch pixels, then mean
        float w9[9];
        #pragma unroll
        for (int t = 0; t < 9; ++t) w9[t] = dw_w[t];
        float dsum = 0.f;
        #pragma unroll
        for (int dy = 0; dy < 2; ++dy) {
            #pragma unroll
            for (int dx = 0; dx < 2; ++dx) {
                const int cy = Y + dy, cx = X + dx;
                #pragma unroll
                for (int ky = 0; ky < 3; ++ky) {
                    const int yy = cy + ky - 1;
                    if (yy < 0 || yy > 27) continue;
                    #pragma unroll
                    for (int kx = 0; kx < 3; ++kx) {
                        const int xx = cx + kx - 1;
                        if (xx < 0 || xx > 27) continue;
                        dsum += xs[yy * 28 + xx] * w9[ky * 3 + kx];
                    }
                }
            }
        }
        const float dpool = 0.25f * dsum;
        const int sp_off = (i + 1) * 16 + (j + 1);
        #pragma unroll 8
        for (int c = 0; c < 32; ++c)
            tile[c * 256 + sp_off] = pw_w[c] * dpool + pw_b[c];

        // quantum patch: RY product state -> U -> PauliZ expectations
        const float p0 = xs[Y * 28 + X],       p1 = xs[Y * 28 + X + 1];
        const float p2 = xs[(Y + 1) * 28 + X], p3 = xs[(Y + 1) * 28 + X + 1];
        float c0, s0, c1, s1, c2, s2, c3, s3;
        sincosf(0.5f * p0, &s0, &c0);
        sincosf(0.5f * p1, &s1, &c1);
        sincosf(0.5f * p2, &s2, &c2);
        sincosf(0.5f * p3, &s3, &c3);
        float a01[4] = {c0 * c1, c0 * s1, s0 * c1, s0 * s1};
        float a23[4] = {c2 * c3, c2 * s3, s2 * c3, s2 * s3};
        float amp[16];
        #pragma unroll
        for (int hi = 0; hi < 4; ++hi)
            #pragma unroll
            for (int lo = 0; lo < 4; ++lo)
                amp[hi * 4 + lo] = a01[hi] * a23[lo];

        float meas[4] = {0.f, 0.f, 0.f, 0.f};
        #pragma unroll
        for (int m = 0; m < 16; ++m) {
            float st = 0.f;
            #pragma unroll
            for (int n = 0; n < 16; ++n) st = fmaf(U[m * 16 + n], amp[n], st);  // uniform -> s_load
            const float pm = st * st;
            meas[0] += ((m >> 3) & 1) ? -pm : pm;
            meas[1] += ((m >> 2) & 1) ? -pm : pm;
            meas[2] += ((m >> 1) & 1) ? -pm : pm;
            meas[3] += (m & 1) ? -pm : pm;
        }
        // reference: meas.reshape(B,784).reshape(B,4,14,14): flat f = i*56+j*4+w
        const int fbase = i * 56 + j * 4;
        #pragma unroll
        for (int w = 0; w < 4; ++w) {
            const int f  = fbase + w;
            const int ch = f / 196;
            const int sp = f - ch * 196;
            tile[(32 + ch) * 256 + (sp / 14 + 1) * 16 + (sp % 14) + 1] = meas[w];
        }
    }
    __syncthreads();

    // ---- phase 3: fused conv 36->128 + relu + pool + folded classifier ----
    const int y    = tid >> 4, xcol = tid & 15;
    const int ysC  = (y < 14) ? y : 13;       // clamp idle lanes in-bounds
    const int xsC  = (xcol < 14) ? xcol : 13;
    const bool sel = (y < 14) && (xcol < 14) && ((y & 1) == 0) && ((xcol & 1) == 0);
    const int fidx = (y >> 1) * 7 + (xcol >> 1);
    const float* tbase = tile + ysC * 16 + xsC;

    float acc11[11];
    #pragma unroll
    for (int k = 0; k < 11; ++k) acc11[k] = 0.f;

    for (int ocb = 0; ocb < 16; ++ocb) {
        const int oc0 = ocb * 8;
        float acc[8];
        #pragma unroll
        for (int r = 0; r < 8; ++r) acc[r] = fus_b[oc0 + r];
        const float* wb = fus_w + oc0 * 324;

        for (int ic = 0; ic < 36; ++ic) {
            float win[9];
            const float* tc = tbase + ic * 256;
            #pragma unroll
            for (int ky = 0; ky < 3; ++ky)
                #pragma unroll
                for (int kx = 0; kx < 3; ++kx)
                    win[ky * 3 + kx] = tc[ky * 16 + kx];
            #pragma unroll
            for (int r = 0; r < 8; ++r) {
                const float* w = wb + r * 324 + ic * 9;   // uniform -> s_load
                #pragma unroll
                for (int t = 0; t < 9; ++t)
                    acc[r] = fmaf(w[t], win[t], acc[r]);
            }
        }
        #pragma unroll
        for (int r = 0; r < 8; ++r) {
            float v = acc[r] > 0.f ? acc[r] : 0.f;   // relu BEFORE pool
            v += __shfl_xor(v, 1, 64);               // pair columns 2j,2j+1
            v += __shfl_xor(v, 16, 64);              // pair rows 2i,2i+1
            if (sel) {
                const float pv = 0.25f * v;          // flat[(oc0+r)*49 + fidx]
                const int f = (oc0 + r) * 49 + fidx;
                #pragma unroll
                for (int k = 0; k < 10; ++k)
                    acc11[k] = fmaf(pv, cls_w[k * 6272 + f], acc11[k]);
                acc11[10] = fmaf(pv, reg_w[f], acc11[10]);
            }
        }
    }
    __syncthreads();   // xs dead; red alias safe

    // ---- phase 4: block-reduce 11 scalars ----
    const int lane = tid & 63, wv = tid >> 6;
    #pragma unroll
    for (int k = 0; k < 11; ++k) {
        float a = acc11[k];
        #pragma unroll
        for (int off = 32; off > 0; off >>= 1) a += __shfl_down(a, off, 64);
        if (lane == 0) red[k * 4 + wv] = a;
    }
    __syncthreads();
    if (tid < 11) {
        const float v = red[tid * 4] + red[tid * 4 + 1] + red[tid * 4 + 2] + red[tid * 4 + 3];
        if (tid < 10) out[b * 10 + tid] = v + cls_b[tid];
        else          out[B * 10 + b]   = v + reg_b[0];
    }
}

extern "C" void kernel_launch(void* const* d_in, const int* in_sizes, int n_in,
                              void* d_out, int out_size, void* d_ws, size_t ws_size,
                              hipStream_t stream) {
    const float* x    = (const float*)d_in[0];
    const float* dw_w = (const float*)d_in[1];
    const float* pw_w = (const float*)d_in[2];
    const float* pw_b = (const float*)d_in[3];
    const float* U    = (const float*)d_in[4];
    const float* fw   = (const float*)d_in[5];
    const float* fb   = (const float*)d_in[6];
    const float* cw   = (const float*)d_in[7];
    const float* cb   = (const float*)d_in[8];
    const float* rw   = (const float*)d_in[9];
    const float* rb   = (const float*)d_in[10];
    const int B = in_sizes[0] / 784;

    quanv_fused<<<B, 256, 0, stream>>>(x, dw_w, pw_w, pw_b, U, fw, fb,
                                       cw, cb, rw, rb, (float*)d_out, B);
}

// Round 3
// 351.545 us; speedup vs baseline: 1.7651x; 1.3854x over previous
//
#include <hip/hip_runtime.h>
#include <math.h>

// One block per image, 256 threads. Fully fused.
//   pre-kernel: transpose fus_w (128,36,3,3) -> wT[ic*9+t][128] in d_ws
//   phase 0: stage x (784) into LDS
//   phase 1: conv3x3+avgpool -> 32 ds channels into padded tile
//   phase 2: quantum patches -> 4 channels into padded tile
//   phase 3: fused conv 36->128 in TWO passes of 64 oc. Each lane owns one
//            spatial position; per ic it reads the 9-value window ONCE from
//            LDS and applies it to 64 output channels whose weights arrive
//            as contiguous s_load_dwordx16 from wT (uniform address).
//            relu + shfl-pool + folded classifier GEMV per pass.
//   phase 4: block-reduce 11 scalars -> out
//
// LDS carve (40,000 B -> 4 blocks/CU):
//   [0, 9216)        tile: 36 ch x 16x16 (zero halo)
//   [9216, 10000)    xs: image (phases 0-2) / aliased: red[44] (phase 4)

#define TILE_F (36 * 256)

__global__ __launch_bounds__(256) void transpose_w(
    const float* __restrict__ fus_w,  // (128,36,3,3)
    float* __restrict__ wT)           // (324,128)
{
    const int gid = blockIdx.x * 256 + threadIdx.x;   // 41472 total
    if (gid < 128 * 324) {
        const int oc = gid & 127;
        const int k  = gid >> 7;                       // ic*9 + t
        wT[gid] = fus_w[oc * 324 + k];
    }
}

__global__ __launch_bounds__(256, 4) void quanv_fused(
    const float* __restrict__ x,      // (B,1,28,28)
    const float* __restrict__ dw_w,   // 9
    const float* __restrict__ pw_w,   // 32
    const float* __restrict__ pw_b,   // 32
    const float* __restrict__ U,      // 16x16
    const float* __restrict__ wT,     // (324,128) transposed fus_w
    const float* __restrict__ fus_b,  // 128
    const float* __restrict__ cls_w,  // 10*6272
    const float* __restrict__ cls_b,  // 10
    const float* __restrict__ reg_w,  // 6272
    const float* __restrict__ reg_b,  // 1
    float* __restrict__ out,          // B*10 logits, then B aux
    int B)
{
    __shared__ float smem[TILE_F + 784];
    float* tile = smem;                 // 36*256
    float* xs   = smem + TILE_F;        // 784 (phases 0-2)
    float* red  = smem + TILE_F;        // alias: 44 floats (phase 4)

    const int b   = blockIdx.x;
    const int tid = threadIdx.x;
    const float* xb = x + b * 784;

    // ---- phase 0 ----
    for (int i = tid; i < TILE_F; i += 256) tile[i] = 0.f;
    for (int i = tid; i < 784; i += 256) xs[i] = xb[i];
    __syncthreads();

    // ---- phases 1+2: per-patch work (196 patches) ----
    if (tid < 196) {
        const int i = tid / 14, j = tid % 14;
        const int Y = 2 * i, X = 2 * j;

        float w9[9];
        #pragma unroll
        for (int t = 0; t < 9; ++t) w9[t] = dw_w[t];
        float dsum = 0.f;
        #pragma unroll
        for (int dy = 0; dy < 2; ++dy) {
            #pragma unroll
            for (int dx = 0; dx < 2; ++dx) {
                const int cy = Y + dy, cx = X + dx;
                #pragma unroll
                for (int ky = 0; ky < 3; ++ky) {
                    const int yy = cy + ky - 1;
                    if (yy < 0 || yy > 27) continue;
                    #pragma unroll
                    for (int kx = 0; kx < 3; ++kx) {
                        const int xx = cx + kx - 1;
                        if (xx < 0 || xx > 27) continue;
                        dsum += xs[yy * 28 + xx] * w9[ky * 3 + kx];
                    }
                }
            }
        }
        const float dpool = 0.25f * dsum;
        const int sp_off = (i + 1) * 16 + (j + 1);
        #pragma unroll 8
        for (int c = 0; c < 32; ++c)
            tile[c * 256 + sp_off] = pw_w[c] * dpool + pw_b[c];

        const float p0 = xs[Y * 28 + X],       p1 = xs[Y * 28 + X + 1];
        const float p2 = xs[(Y + 1) * 28 + X], p3 = xs[(Y + 1) * 28 + X + 1];
        float c0, s0, c1, s1, c2, s2, c3, s3;
        sincosf(0.5f * p0, &s0, &c0);
        sincosf(0.5f * p1, &s1, &c1);
        sincosf(0.5f * p2, &s2, &c2);
        sincosf(0.5f * p3, &s3, &c3);
        float a01[4] = {c0 * c1, c0 * s1, s0 * c1, s0 * s1};
        float a23[4] = {c2 * c3, c2 * s3, s2 * c3, s2 * s3};
        float amp[16];
        #pragma unroll
        for (int hi = 0; hi < 4; ++hi)
            #pragma unroll
            for (int lo = 0; lo < 4; ++lo)
                amp[hi * 4 + lo] = a01[hi] * a23[lo];

        float meas[4] = {0.f, 0.f, 0.f, 0.f};
        #pragma unroll
        for (int m = 0; m < 16; ++m) {
            float st = 0.f;
            #pragma unroll
            for (int n = 0; n < 16; ++n) st = fmaf(U[m * 16 + n], amp[n], st);
            const float pm = st * st;
            meas[0] += ((m >> 3) & 1) ? -pm : pm;
            meas[1] += ((m >> 2) & 1) ? -pm : pm;
            meas[2] += ((m >> 1) & 1) ? -pm : pm;
            meas[3] += (m & 1) ? -pm : pm;
        }
        const int fbase = i * 56 + j * 4;
        #pragma unroll
        for (int w = 0; w < 4; ++w) {
            const int f  = fbase + w;
            const int ch = f / 196;
            const int sp = f - ch * 196;
            tile[(32 + ch) * 256 + (sp / 14 + 1) * 16 + (sp % 14) + 1] = meas[w];
        }
    }
    __syncthreads();

    // ---- phase 3: conv 36->128, two passes of 64 oc ----
    const int y    = tid >> 4, xcol = tid & 15;
    const int ysC  = (y < 14) ? y : 13;
    const int xsC  = (xcol < 14) ? xcol : 13;
    const bool sel = (y < 14) && (xcol < 14) && ((y & 1) == 0) && ((xcol & 1) == 0);
    const int fidx = (y >> 1) * 7 + (xcol >> 1);
    const float* tbase = tile + ysC * 16 + xsC;

    float acc11[11];
    #pragma unroll
    for (int k = 0; k < 11; ++k) acc11[k] = 0.f;

    for (int pass = 0; pass < 2; ++pass) {
        const int oc0 = pass * 64;
        float acc[64];
        #pragma unroll
        for (int r = 0; r < 64; ++r) acc[r] = fus_b[oc0 + r];

        for (int ic = 0; ic < 36; ++ic) {
            float win[9];
            const float* tc = tbase + ic * 256;
            #pragma unroll
            for (int ky = 0; ky < 3; ++ky)
                #pragma unroll
                for (int kx = 0; kx < 3; ++kx)
                    win[ky * 3 + kx] = tc[ky * 16 + kx];
            const float* wb = wT + ic * 9 * 128 + oc0;   // uniform -> s_load_dwordx16
            #pragma unroll
            for (int t = 0; t < 9; ++t) {
                const float wv = win[t];
                const float* wrow = wb + t * 128;
                #pragma unroll
                for (int r = 0; r < 64; ++r)
                    acc[r] = fmaf(wrow[r], wv, acc[r]);
            }
        }
        // relu -> pool -> folded classifier for these 64 channels
        #pragma unroll
        for (int r = 0; r < 64; ++r) {
            float v = acc[r] > 0.f ? acc[r] : 0.f;   // relu BEFORE pool
            v += __shfl_xor(v, 1, 64);               // pair columns
            v += __shfl_xor(v, 16, 64);              // pair rows
            if (sel) {
                const float pv = 0.25f * v;
                const int f = (oc0 + r) * 49 + fidx;
                #pragma unroll
                for (int k = 0; k < 10; ++k)
                    acc11[k] = fmaf(pv, cls_w[k * 6272 + f], acc11[k]);
                acc11[10] = fmaf(pv, reg_w[f], acc11[10]);
            }
        }
    }
    __syncthreads();   // xs dead; red alias safe

    // ---- phase 4: block-reduce 11 scalars ----
    const int lane = tid & 63, wv = tid >> 6;
    #pragma unroll
    for (int k = 0; k < 11; ++k) {
        float a = acc11[k];
        #pragma unroll
        for (int off = 32; off > 0; off >>= 1) a += __shfl_down(a, off, 64);
        if (lane == 0) red[k * 4 + wv] = a;
    }
    __syncthreads();
    if (tid < 11) {
        const float v = red[tid * 4] + red[tid * 4 + 1] + red[tid * 4 + 2] + red[tid * 4 + 3];
        if (tid < 10) out[b * 10 + tid] = v + cls_b[tid];
        else          out[B * 10 + b]   = v + reg_b[0];
    }
}

extern "C" void kernel_launch(void* const* d_in, const int* in_sizes, int n_in,
                              void* d_out, int out_size, void* d_ws, size_t ws_size,
                              hipStream_t stream) {
    const float* x    = (const float*)d_in[0];
    const float* dw_w = (const float*)d_in[1];
    const float* pw_w = (const float*)d_in[2];
    const float* pw_b = (const float*)d_in[3];
    const float* U    = (const float*)d_in[4];
    const float* fw   = (const float*)d_in[5];
    const float* fb   = (const float*)d_in[6];
    const float* cw   = (const float*)d_in[7];
    const float* cb   = (const float*)d_in[8];
    const float* rw   = (const float*)d_in[9];
    const float* rb   = (const float*)d_in[10];
    const int B = in_sizes[0] / 784;

    float* wT = (float*)d_ws;   // 324*128 floats = 165,888 B

    transpose_w<<<(128 * 324 + 255) / 256, 256, 0, stream>>>(fw, wT);
    quanv_fused<<<B, 256, 0, stream>>>(x, dw_w, pw_w, pw_b, U, wT, fb,
                                       cw, cb, rw, rb, (float*)d_out, B);
}

// Round 4
// 150.582 us; speedup vs baseline: 4.1206x; 2.3346x over previous
//
#include <hip/hip_runtime.h>
#include <math.h>

// Fully fused quanvolution. The 36->128 3x3 conv runs on bf16 MFMA
// (v_mfma_f32_32x32x16_bf16) as 9 shift-GEMMs with ic padded 36->48 (3 K-steps
// of 16 per tap). M is enumerated pooling-aligned: m' = cell*4 + sub, so each
// lane's acc quad (r&3) is one complete 2x2 pooled cell -> relu+pool+classifier
// fold are in-lane (no shuffles, no flat buffer).
//
// prep kernel (d_ws):
//   [0, 110592)        bfrag: B fragments in exact MFMA B-operand order,
//                      [nt][t*3+ks][lane][8 bf16] (zero-padded ic 36..47)
//   [110592, +301056)  cls_wT[f][12] fp32: k0..9 = cls_w, k10 = reg_w, k11 = 0
//
// main kernel LDS:
//   actT[256 rows][48 ic] bf16 (24576 B), rows = padded 16x16 spatial grid,
//   16B-slot rotated by (row_y mod 6) to spread LDS banks (stride 96 B is
//   otherwise x-only banked ~10-way).
//   xs[784] fp32 staging, red[48] reduction scratch. Total ~27.9 KB -> 4 blk/CU.

typedef __bf16 bf16x8 __attribute__((ext_vector_type(8)));
typedef float  f32x16 __attribute__((ext_vector_type(16)));

union Pack8 { __bf16 h[8]; uint4 v; };

__global__ __launch_bounds__(256) void prep(
    const float* __restrict__ fus_w,  // (128,36,3,3)
    const float* __restrict__ cls_w,  // (10,6272)
    const float* __restrict__ reg_w,  // (6272)
    __bf16* __restrict__ bfrag,       // 6912 * 8 bf16
    float* __restrict__ clsT)         // 6272 * 12
{
    const int gid = blockIdx.x * 256 + threadIdx.x;
    if (gid < 6912) {
        const int lane = gid & 63;
        const int rest = gid >> 6;          // 0..107
        const int m  = rest % 27;           // t*3 + ks
        const int nt = rest / 27;
        const int t  = m / 3, ks = m - t * 3;
        const int n  = nt * 32 + (lane & 31);
        const int kb = ks * 16 + (lane >> 5) * 8;
        Pack8 pk;
        #pragma unroll
        for (int j = 0; j < 8; ++j) {
            const int ic = kb + j;
            const float v = (ic < 36) ? fus_w[n * 324 + ic * 9 + t] : 0.f;
            pk.h[j] = (__bf16)v;
        }
        ((uint4*)bfrag)[gid] = pk.v;
    } else {
        const int g = gid - 6912;
        if (g < 6272 * 12) {
            const int f = g / 12, k = g - f * 12;
            float v = 0.f;
            if (k < 10) v = cls_w[k * 6272 + f];
            else if (k == 10) v = reg_w[f];
            clsT[g] = v;
        }
    }
}

__global__ __launch_bounds__(256, 4) void quanv_fused(
    const float* __restrict__ x,      // (B,1,28,28)
    const float* __restrict__ dw_w,   // 9
    const float* __restrict__ pw_w,   // 32
    const float* __restrict__ pw_b,   // 32
    const float* __restrict__ U,      // 16x16
    const __bf16* __restrict__ bfrag, // B fragments
    const float* __restrict__ fus_b,  // 128
    const float* __restrict__ clsT,   // (6272,12)
    const float* __restrict__ cls_b,  // 10
    const float* __restrict__ reg_b,  // 1
    float* __restrict__ out,          // B*10 logits, then B aux
    int B)
{
    __shared__ __align__(16) __bf16 actT[256 * 48];  // 24576 B
    __shared__ float xs[784];
    __shared__ float red[48];

    const int b   = blockIdx.x;
    const int tid = threadIdx.x;
    const float* xb = x + b * 784;

    // ---- phase 0: zero actT (halo + ic padding), stage image ----
    {
        uint4 z; z.x = 0; z.y = 0; z.z = 0; z.w = 0;
        for (int i = tid; i < 1536; i += 256) ((uint4*)actT)[i] = z;
        for (int i = tid; i < 784; i += 256) xs[i] = xb[i];
    }
    __syncthreads();

    // ---- phases 1+2: per-patch work (196 patches) ----
    if (tid < 196) {
        const int i = tid / 14, j = tid % 14;
        const int Y = 2 * i, X = 2 * j;

        float w9[9];
        #pragma unroll
        for (int t = 0; t < 9; ++t) w9[t] = dw_w[t];
        float dsum = 0.f;
        #pragma unroll
        for (int dy = 0; dy < 2; ++dy) {
            #pragma unroll
            for (int dx = 0; dx < 2; ++dx) {
                const int cy = Y + dy, cx = X + dx;
                #pragma unroll
                for (int ky = 0; ky < 3; ++ky) {
                    const int yy = cy + ky - 1;
                    if (yy < 0 || yy > 27) continue;
                    #pragma unroll
                    for (int kx = 0; kx < 3; ++kx) {
                        const int xx = cx + kx - 1;
                        if (xx < 0 || xx > 27) continue;
                        dsum += xs[yy * 28 + xx] * w9[ky * 3 + kx];
                    }
                }
            }
        }
        const float dpool = 0.25f * dsum;

        // ds channels 0..31 -> row sp_o, chunks 0..3 (slot-rotated)
        const int sp_o  = (i + 1) * 16 + (j + 1);
        const int rot_o = (i + 1) % 6;           // row_y mod 6
        #pragma unroll
        for (int c8 = 0; c8 < 4; ++c8) {
            Pack8 pk;
            #pragma unroll
            for (int e = 0; e < 8; ++e)
                pk.h[e] = (__bf16)(pw_w[c8 * 8 + e] * dpool + pw_b[c8 * 8 + e]);
            int slot = c8 + rot_o; if (slot >= 6) slot -= 6;
            ((uint4*)actT)[sp_o * 6 + slot] = pk.v;
        }

        // quantum patch
        const float p0 = xs[Y * 28 + X],       p1 = xs[Y * 28 + X + 1];
        const float p2 = xs[(Y + 1) * 28 + X], p3 = xs[(Y + 1) * 28 + X + 1];
        float c0, s0, c1, s1, c2, s2, c3, s3;
        sincosf(0.5f * p0, &s0, &c0);
        sincosf(0.5f * p1, &s1, &c1);
        sincosf(0.5f * p2, &s2, &c2);
        sincosf(0.5f * p3, &s3, &c3);
        float a01[4] = {c0 * c1, c0 * s1, s0 * c1, s0 * s1};
        float a23[4] = {c2 * c3, c2 * s3, s2 * c3, s2 * s3};
        float amp[16];
        #pragma unroll
        for (int hi = 0; hi < 4; ++hi)
            #pragma unroll
            for (int lo = 0; lo < 4; ++lo)
                amp[hi * 4 + lo] = a01[hi] * a23[lo];

        float meas[4] = {0.f, 0.f, 0.f, 0.f};
        #pragma unroll
        for (int m = 0; m < 16; ++m) {
            float st = 0.f;
            #pragma unroll
            for (int n = 0; n < 16; ++n) st = fmaf(U[m * 16 + n], amp[n], st);
            const float pm = st * st;
            meas[0] += ((m >> 3) & 1) ? -pm : pm;
            meas[1] += ((m >> 2) & 1) ? -pm : pm;
            meas[2] += ((m >> 1) & 1) ? -pm : pm;
            meas[3] += (m & 1) ? -pm : pm;
        }
        const int fbase = i * 56 + j * 4;
        #pragma unroll
        for (int w = 0; w < 4; ++w) {
            const int f  = fbase + w;
            const int ch = f / 196;               // 0..3 -> ic 32+ch
            const int sp = f - ch * 196;
            const int r2 = sp / 14 + 1, c2i = sp % 14 + 1;
            const int sp2 = r2 * 16 + c2i;
            int slot = 4 + r2 % 6; if (slot >= 6) slot -= 6;
            actT[sp2 * 48 + slot * 8 + ch] = (__bf16)meas[w];
        }
    }
    __syncthreads();

    // ---- phase 3: MFMA conv 36->128 (9 shift-GEMMs) + in-lane pool/classifier ----
    const int lane = tid & 63, nt = tid >> 6;
    const int l31  = lane & 31, hk = lane >> 5;
    const float fb_l = fus_b[nt * 32 + l31];
    const bf16x8* __restrict__ bptr = ((const bf16x8*)bfrag) + (nt * 27 * 64 + lane);

    float a11[11];
    #pragma unroll
    for (int k = 0; k < 11; ++k) a11[k] = 0.f;

    for (int mt = 0; mt < 7; ++mt) {
        // lane's A-row: m' = mt*32 + l31 -> pooled cell + sub-pixel
        const int mp   = mt * 32 + l31;
        int cell = mp >> 2;
        const int cc = (cell < 49) ? cell : 48;   // clamp garbage rows in-bounds
        const int py = (cc * 9363) >> 16;         // cc/7 for cc<56
        const int px = cc - py * 7;
        const int yy = 2 * py + ((mp >> 1) & 1);
        const int xx = 2 * px + (mp & 1);
        const int rowbase = yy * 16 + xx;
        const int ym6 = yy - 6 * ((yy * 43) >> 8);  // yy mod 6, yy < 24

        f32x16 acc = {0.f,0.f,0.f,0.f,0.f,0.f,0.f,0.f,
                      0.f,0.f,0.f,0.f,0.f,0.f,0.f,0.f};

        #pragma unroll
        for (int t = 0; t < 9; ++t) {
            const int ky = t / 3, kx = t - ky * 3;
            int rot = ym6 + ky; if (rot >= 6) rot -= 6;
            const int row = rowbase + ky * 16 + kx;
            #pragma unroll
            for (int ks = 0; ks < 3; ++ks) {
                int slot = 2 * ks + hk + rot; if (slot >= 6) slot -= 6;
                const bf16x8 af = *(const bf16x8*)(actT + row * 48 + slot * 8);
                const bf16x8 bf = bptr[(t * 3 + ks) * 64];
                acc = __builtin_amdgcn_mfma_f32_32x32x16_bf16(af, bf, acc, 0, 0, 0);
            }
        }

        // epilogue: C rows (r&3) of quad q form one pooled cell, in-lane
        #pragma unroll
        for (int q = 0; q < 4; ++q) {
            float pv = 0.f;
            #pragma unroll
            for (int s = 0; s < 4; ++s) {
                const float v = acc[q * 4 + s] + fb_l;
                pv += (v > 0.f ? v : 0.f);
            }
            pv *= 0.25f;
            const int cellq = mt * 8 + 2 * q + hk;
            if (cellq < 49) {
                const float4* cw =
                    (const float4*)(clsT + ((nt * 32 + l31) * 49 + cellq) * 12);
                const float4 w0 = cw[0], w1 = cw[1], w2 = cw[2];
                a11[0] += pv * w0.x; a11[1] += pv * w0.y;
                a11[2] += pv * w0.z; a11[3] += pv * w0.w;
                a11[4] += pv * w1.x; a11[5] += pv * w1.y;
                a11[6] += pv * w1.z; a11[7] += pv * w1.w;
                a11[8] += pv * w2.x; a11[9] += pv * w2.y;
                a11[10] += pv * w2.z;
            }
        }
    }
    __syncthreads();

    // ---- phase 4: block-reduce 11 scalars ----
    const int wv = tid >> 6;
    #pragma unroll
    for (int k = 0; k < 11; ++k) {
        float a = a11[k];
        #pragma unroll
        for (int off = 32; off > 0; off >>= 1) a += __shfl_down(a, off, 64);
        if (lane == 0) red[k * 4 + wv] = a;
    }
    __syncthreads();
    if (tid < 11) {
        const float v = red[tid * 4] + red[tid * 4 + 1] + red[tid * 4 + 2] + red[tid * 4 + 3];
        if (tid < 10) out[b * 10 + tid] = v + cls_b[tid];
        else          out[B * 10 + b]   = v + reg_b[0];
    }
}

extern "C" void kernel_launch(void* const* d_in, const int* in_sizes, int n_in,
                              void* d_out, int out_size, void* d_ws, size_t ws_size,
                              hipStream_t stream) {
    const float* x    = (const float*)d_in[0];
    const float* dw_w = (const float*)d_in[1];
    const float* pw_w = (const float*)d_in[2];
    const float* pw_b = (const float*)d_in[3];
    const float* U    = (const float*)d_in[4];
    const float* fw   = (const float*)d_in[5];
    const float* fb   = (const float*)d_in[6];
    const float* cw   = (const float*)d_in[7];
    const float* cb   = (const float*)d_in[8];
    const float* rw   = (const float*)d_in[9];
    const float* rb   = (const float*)d_in[10];
    const int B = in_sizes[0] / 784;

    __bf16* bfrag = (__bf16*)d_ws;                       // 110,592 B
    float*  clsT  = (float*)((char*)d_ws + 110592);      // 301,056 B

    prep<<<(6912 + 6272 * 12 + 255) / 256, 256, 0, stream>>>(fw, cw, rw, bfrag, clsT);
    quanv_fused<<<B, 256, 0, stream>>>(x, dw_w, pw_w, pw_b, U, bfrag, fb,
                                       clsT, cb, rb, (float*)d_out, B);
}

// Round 5
// 126.124 us; speedup vs baseline: 4.9197x; 1.1939x over previous
//
#include <hip/hip_runtime.h>
#include <math.h>

// Fully fused quanvolution. 36->128 3x3 conv on bf16 MFMA
// (v_mfma_f32_32x32x16_bf16) as 9 shift-GEMMs, ic padded 36->48.
// M enumerated pooling-aligned: m' = cell*4 + sub, so each lane's acc quad
// is one complete 2x2 pooled cell -> relu+pool in-lane.
//
// Round-5 changes vs round-4:
//   * all 27 B-fragments hoisted to registers (inner loop = ds_read+mfma only)
//   * classifier un-folded: pooled values -> LDS flat[6272] fp32, then a
//     coalesced GEMV from the ORIGINAL cls_w/reg_w layouts (round-2 pattern).
//     clsT prep removed entirely.
//   * __launch_bounds__(256,3): 3 blocks/CU, VGPR cap ~170 for the hoist.
//
// d_ws: bfrag only — B fragments in exact MFMA B-operand order,
//       [nt][t*3+ks][lane][8 bf16], zero-padded ic 36..47. 110,592 B.
//
// LDS (52,992 B -> 3 blocks/CU):
//   actT[256][48] bf16 (24576) — padded 16x16 spatial grid, 16B-slot rotated
//     by (row_y mod 6) to spread banks (stride 96 B is x-only banked otherwise)
//   flat[6272] fp32 (25088) — pooled activations (write stride 49 floats:
//     49 mod 32 = 17, odd -> all banks covered, conflict-free)
//   xs[784] fp32 (3136), red[48] (192)

typedef __bf16 bf16x8 __attribute__((ext_vector_type(8)));
typedef float  f32x16 __attribute__((ext_vector_type(16)));

union Pack8 { __bf16 h[8]; uint4 v; };

__global__ __launch_bounds__(256) void prep(
    const float* __restrict__ fus_w,  // (128,36,3,3)
    __bf16* __restrict__ bfrag)       // 6912 * 8 bf16
{
    const int gid = blockIdx.x * 256 + threadIdx.x;
    if (gid < 6912) {
        const int lane = gid & 63;
        const int rest = gid >> 6;          // 0..107
        const int m  = rest % 27;           // t*3 + ks
        const int nt = rest / 27;
        const int t  = m / 3, ks = m - t * 3;
        const int n  = nt * 32 + (lane & 31);
        const int kb = ks * 16 + (lane >> 5) * 8;
        Pack8 pk;
        #pragma unroll
        for (int j = 0; j < 8; ++j) {
            const int ic = kb + j;
            const float v = (ic < 36) ? fus_w[n * 324 + ic * 9 + t] : 0.f;
            pk.h[j] = (__bf16)v;
        }
        ((uint4*)bfrag)[gid] = pk.v;
    }
}

__global__ __launch_bounds__(256, 3) void quanv_fused(
    const float* __restrict__ x,      // (B,1,28,28)
    const float* __restrict__ dw_w,   // 9
    const float* __restrict__ pw_w,   // 32
    const float* __restrict__ pw_b,   // 32
    const float* __restrict__ U,      // 16x16
    const __bf16* __restrict__ bfrag, // B fragments
    const float* __restrict__ fus_b,  // 128
    const float* __restrict__ cls_w,  // (10,6272)
    const float* __restrict__ cls_b,  // 10
    const float* __restrict__ reg_w,  // 6272
    const float* __restrict__ reg_b,  // 1
    float* __restrict__ out,          // B*10 logits, then B aux
    int B)
{
    __shared__ __align__(16) __bf16 actT[256 * 48];  // 24576 B
    __shared__ float flat[6272];                     // 25088 B
    __shared__ float xs[784];                        // 3136 B
    __shared__ float red[48];                        // 192 B

    const int b   = blockIdx.x;
    const int tid = threadIdx.x;
    const float* xb = x + b * 784;

    // ---- phase 0: zero actT (halo + ic padding), stage image ----
    {
        uint4 z; z.x = 0; z.y = 0; z.z = 0; z.w = 0;
        for (int i = tid; i < 1536; i += 256) ((uint4*)actT)[i] = z;
        for (int i = tid; i < 784; i += 256) xs[i] = xb[i];
    }
    __syncthreads();

    // ---- phases 1+2: per-patch work (196 patches) ----
    if (tid < 196) {
        const int i = tid / 14, j = tid % 14;
        const int Y = 2 * i, X = 2 * j;

        float w9[9];
        #pragma unroll
        for (int t = 0; t < 9; ++t) w9[t] = dw_w[t];
        float dsum = 0.f;
        #pragma unroll
        for (int dy = 0; dy < 2; ++dy) {
            #pragma unroll
            for (int dx = 0; dx < 2; ++dx) {
                const int cy = Y + dy, cx = X + dx;
                #pragma unroll
                for (int ky = 0; ky < 3; ++ky) {
                    const int yy = cy + ky - 1;
                    if (yy < 0 || yy > 27) continue;
                    #pragma unroll
                    for (int kx = 0; kx < 3; ++kx) {
                        const int xx = cx + kx - 1;
                        if (xx < 0 || xx > 27) continue;
                        dsum += xs[yy * 28 + xx] * w9[ky * 3 + kx];
                    }
                }
            }
        }
        const float dpool = 0.25f * dsum;

        // ds channels 0..31 -> row sp_o, chunks 0..3 (slot-rotated)
        const int sp_o  = (i + 1) * 16 + (j + 1);
        const int rot_o = (i + 1) % 6;           // row_y mod 6
        #pragma unroll
        for (int c8 = 0; c8 < 4; ++c8) {
            Pack8 pk;
            #pragma unroll
            for (int e = 0; e < 8; ++e)
                pk.h[e] = (__bf16)(pw_w[c8 * 8 + e] * dpool + pw_b[c8 * 8 + e]);
            int slot = c8 + rot_o; if (slot >= 6) slot -= 6;
            ((uint4*)actT)[sp_o * 6 + slot] = pk.v;
        }

        // quantum patch
        const float p0 = xs[Y * 28 + X],       p1 = xs[Y * 28 + X + 1];
        const float p2 = xs[(Y + 1) * 28 + X], p3 = xs[(Y + 1) * 28 + X + 1];
        float c0, s0, c1, s1, c2, s2, c3, s3;
        sincosf(0.5f * p0, &s0, &c0);
        sincosf(0.5f * p1, &s1, &c1);
        sincosf(0.5f * p2, &s2, &c2);
        sincosf(0.5f * p3, &s3, &c3);
        float a01[4] = {c0 * c1, c0 * s1, s0 * c1, s0 * s1};
        float a23[4] = {c2 * c3, c2 * s3, s2 * c3, s2 * s3};
        float amp[16];
        #pragma unroll
        for (int hi = 0; hi < 4; ++hi)
            #pragma unroll
            for (int lo = 0; lo < 4; ++lo)
                amp[hi * 4 + lo] = a01[hi] * a23[lo];

        float meas[4] = {0.f, 0.f, 0.f, 0.f};
        #pragma unroll
        for (int m = 0; m < 16; ++m) {
            float st = 0.f;
            #pragma unroll
            for (int n = 0; n < 16; ++n) st = fmaf(U[m * 16 + n], amp[n], st);
            const float pm = st * st;
            meas[0] += ((m >> 3) & 1) ? -pm : pm;
            meas[1] += ((m >> 2) & 1) ? -pm : pm;
            meas[2] += ((m >> 1) & 1) ? -pm : pm;
            meas[3] += (m & 1) ? -pm : pm;
        }
        const int fbase = i * 56 + j * 4;
        #pragma unroll
        for (int w = 0; w < 4; ++w) {
            const int f  = fbase + w;
            const int ch = f / 196;               // 0..3 -> ic 32+ch
            const int sp = f - ch * 196;
            const int r2 = sp / 14 + 1, c2i = sp % 14 + 1;
            const int sp2 = r2 * 16 + c2i;
            int slot = 4 + r2 % 6; if (slot >= 6) slot -= 6;
            actT[sp2 * 48 + slot * 8 + ch] = (__bf16)meas[w];
        }
    }
    __syncthreads();

    // ---- phase 3: MFMA conv 36->128 (9 shift-GEMMs), B-frags in registers ----
    const int lane = tid & 63, nt = tid >> 6;
    const int l31  = lane & 31, hk = lane >> 5;
    const float fb_l = fus_b[nt * 32 + l31];

    bf16x8 bfr[27];
    {
        const bf16x8* __restrict__ bp = ((const bf16x8*)bfrag) + (nt * 27 * 64 + lane);
        #pragma unroll
        for (int m = 0; m < 27; ++m) bfr[m] = bp[m * 64];
    }

    for (int mt = 0; mt < 7; ++mt) {
        // lane's A-row: m' = mt*32 + l31 -> pooled cell + sub-pixel
        const int mp   = mt * 32 + l31;
        int cell = mp >> 2;
        const int cc = (cell < 49) ? cell : 48;   // clamp garbage rows in-bounds
        const int py = (cc * 9363) >> 16;         // cc/7 for cc<56
        const int px = cc - py * 7;
        const int yy = 2 * py + ((mp >> 1) & 1);
        const int xx = 2 * px + (mp & 1);
        const int rowbase = yy * 16 + xx;
        const int ym6 = yy - 6 * ((yy * 43) >> 8);  // yy mod 6, yy < 24

        f32x16 acc = {0.f,0.f,0.f,0.f,0.f,0.f,0.f,0.f,
                      0.f,0.f,0.f,0.f,0.f,0.f,0.f,0.f};

        #pragma unroll
        for (int t = 0; t < 9; ++t) {
            const int ky = t / 3, kx = t - ky * 3;
            int rot = ym6 + ky; if (rot >= 6) rot -= 6;
            const int row = rowbase + ky * 16 + kx;
            #pragma unroll
            for (int ks = 0; ks < 3; ++ks) {
                int slot = 2 * ks + hk + rot; if (slot >= 6) slot -= 6;
                const bf16x8 af = *(const bf16x8*)(actT + row * 48 + slot * 8);
                acc = __builtin_amdgcn_mfma_f32_32x32x16_bf16(af, bfr[t * 3 + ks],
                                                              acc, 0, 0, 0);
            }
        }

        // epilogue: relu+pool in-lane, pooled value -> LDS flat
        #pragma unroll
        for (int q = 0; q < 4; ++q) {
            float pv = 0.f;
            #pragma unroll
            for (int s = 0; s < 4; ++s) {
                const float v = acc[q * 4 + s] + fb_l;
                pv += (v > 0.f ? v : 0.f);
            }
            pv *= 0.25f;
            const int cellq = mt * 8 + 2 * q + hk;
            if (cellq < 49)
                flat[(nt * 32 + l31) * 49 + cellq] = pv;   // stride 49: conflict-free
        }
    }
    __syncthreads();

    // ---- phase 4: coalesced classifier GEMV (10 logits + 1 aux) ----
    float a11[11];
    #pragma unroll
    for (int k = 0; k < 11; ++k) a11[k] = 0.f;
    for (int f = tid; f < 6272; f += 256) {
        const float v = flat[f];
        #pragma unroll
        for (int k = 0; k < 10; ++k)
            a11[k] = fmaf(v, cls_w[k * 6272 + f], a11[k]);
        a11[10] = fmaf(v, reg_w[f], a11[10]);
    }
    const int wv = tid >> 6;
    #pragma unroll
    for (int k = 0; k < 11; ++k) {
        float a = a11[k];
        #pragma unroll
        for (int off = 32; off > 0; off >>= 1) a += __shfl_down(a, off, 64);
        if (lane == 0) red[k * 4 + wv] = a;
    }
    __syncthreads();
    if (tid < 11) {
        const float v = red[tid * 4] + red[tid * 4 + 1] + red[tid * 4 + 2] + red[tid * 4 + 3];
        if (tid < 10) out[b * 10 + tid] = v + cls_b[tid];
        else          out[B * 10 + b]   = v + reg_b[0];
    }
}

extern "C" void kernel_launch(void* const* d_in, const int* in_sizes, int n_in,
                              void* d_out, int out_size, void* d_ws, size_t ws_size,
                              hipStream_t stream) {
    const float* x    = (const float*)d_in[0];
    const float* dw_w = (const float*)d_in[1];
    const float* pw_w = (const float*)d_in[2];
    const float* pw_b = (const float*)d_in[3];
    const float* U    = (const float*)d_in[4];
    const float* fw   = (const float*)d_in[5];
    const float* fb   = (const float*)d_in[6];
    const float* cw   = (const float*)d_in[7];
    const float* cb   = (const float*)d_in[8];
    const float* rw   = (const float*)d_in[9];
    const float* rb   = (const float*)d_in[10];
    const int B = in_sizes[0] / 784;

    __bf16* bfrag = (__bf16*)d_ws;   // 110,592 B

    prep<<<27, 256, 0, stream>>>(fw, bfrag);
    quanv_fused<<<B, 256, 0, stream>>>(x, dw_w, pw_w, pw_b, U, bfrag, fb,
                                       cw, cb, rw, rb, (float*)d_out, B);
}